// Round 1
// baseline (1001.759 us; speedup 1.0000x reference)
//
#include <hip/hip_runtime.h>
#include <hip/hip_bf16.h>

#define BB 4
#define NH 8
#define HD 64
#define CC 512
#define LL 2048
#define KK 1536   // C*3, K index = t*512 + ci

typedef float f32x4 __attribute__((ext_vector_type(4)));
typedef short bf16x8 __attribute__((ext_vector_type(8)));

static __device__ __forceinline__ ushort f2bf(float f) {
  union { float f; unsigned u; } v; v.f = f;
  unsigned r = v.u + 0x7fffu + ((v.u >> 16) & 1u);   // RNE
  return (ushort)(r >> 16);
}
static __device__ __forceinline__ float bf2f(ushort u) {
  union { unsigned u; float f; } v; v.u = ((unsigned)u) << 16;
  return v.f;
}
static __device__ __forceinline__ float loadf(const float* p, int i) { return p[i]; }
static __device__ __forceinline__ float loadf(const ushort* p, int i) { return bf2f(p[i]); }

// ---------------------------------------------------------------------------
// Weight prep: W[co][ci][t] fp32 -> W'[co][t*512+ci] bf16, for all 4 convs.
// ---------------------------------------------------------------------------
__global__ void prep_w(const float* __restrict__ w0, const float* __restrict__ w1,
                       const float* __restrict__ w2, const float* __restrict__ w3,
                       ushort* __restrict__ out)
{
  int i = blockIdx.x * 256 + threadIdx.x;
  const int per = CC * KK;
  if (i >= 4 * per) return;
  int cidx = i / per;
  int rem  = i - cidx * per;
  int co   = rem / KK;
  int kk   = rem - co * KK;
  int t = kk >> 9, ci = kk & 511;
  const float* w = (cidx == 0) ? w0 : (cidx == 1) ? w1 : (cidx == 2) ? w2 : w3;
  out[i] = f2bf(w[((size_t)co * CC + ci) * 3 + t]);
}

// ---------------------------------------------------------------------------
// conv1d(k=3,same) as implicit GEMM, bf16 MFMA 16x16x32.
// Tile: M=64 (co) x N=128 (l), BK=32.  4 waves: 2x2 over (co 32, l 64),
// each wave 2x4 mfma tiles.  A = W' [co][K], Bt = xpatch [l][K] staged in LDS.
// MODE 0: out = heads [b][h][x][d] bf16   (q,k)
// MODE 1: out = heads-T [b][h][d][x] bf16 (v)
// MODE 2: out = [b][co][l] fp32           (final fc)
// ---------------------------------------------------------------------------
template<int MODE, typename TIn>
__global__ __launch_bounds__(256, 2)
void conv_k(const TIn* __restrict__ xin, const ushort* __restrict__ Wt,
            const float* __restrict__ bias, void* __restrict__ outp)
{
  const int b   = blockIdx.z;
  const int co0 = blockIdx.y * 64;
  const int l0  = blockIdx.x * 128;
  const int tid = threadIdx.x;
  const int lane = tid & 63;
  const int w    = tid >> 6;
  const int col  = lane & 15, quad = lane >> 4;

  __shared__ ushort Asl[64 * 40];    // stride 40: 2-way-max bank pattern, 16B aligned rows
  __shared__ ushort Bsl[128 * 40];

  const TIn* xb = xin + (size_t)b * CC * LL;

  f32x4 acc[2][4] = {};
  const int cm0 = (w & 1) * 32;
  const int cn0 = (w >> 1) * 64;

  for (int k0 = 0; k0 < KK; k0 += 32) {
    // stage A: 64 rows x 32 bf16 (each thread one uint4 = 8 bf16)
    {
      const int row = tid >> 2;
      const int c0  = (tid & 3) * 8;
      const uint4 a = *(const uint4*)(Wt + (size_t)(co0 + row) * KK + k0 + c0);
      *(uint4*)&Asl[row * 40 + c0] = a;
    }
    // stage B (transposed): Bt[l][ci] = x[ci0+ci][l0+l-1+t]; coalesced lane-per-l reads
    {
      const int t   = k0 >> 9;
      const int ci0 = k0 & 511;
#pragma unroll
      for (int rr = 0; rr < 8; ++rr) {
        const int ci = w * 8 + rr;
        const TIn* xr = xb + (size_t)(ci0 + ci) * LL;
#pragma unroll
        for (int it = 0; it < 2; ++it) {
          const int lidx = it * 64 + lane;
          const int li = l0 + lidx - 1 + t;
          float vv = (li >= 0 && li < LL) ? loadf(xr, li) : 0.f;
          Bsl[lidx * 40 + ci] = f2bf(vv);
        }
      }
    }
    __syncthreads();
    bf16x8 af[2], bfr[4];
#pragma unroll
    for (int i = 0; i < 2; ++i)
      af[i] = *(const bf16x8*)&Asl[(cm0 + i * 16 + col) * 40 + quad * 8];
#pragma unroll
    for (int j = 0; j < 4; ++j)
      bfr[j] = *(const bf16x8*)&Bsl[(cn0 + j * 16 + col) * 40 + quad * 8];
#pragma unroll
    for (int i = 0; i < 2; ++i)
#pragma unroll
      for (int j = 0; j < 4; ++j)
        acc[i][j] = __builtin_amdgcn_mfma_f32_16x16x32_bf16(af[i], bfr[j], acc[i][j], 0, 0, 0);
    __syncthreads();
  }

  // epilogue: C/D layout row = quad*4+r (co), col = lane&15 (l)
#pragma unroll
  for (int i = 0; i < 2; ++i) {
#pragma unroll
    for (int r = 0; r < 4; ++r) {
      const int co = co0 + cm0 + i * 16 + quad * 4 + r;
      const float bi = bias[co];
#pragma unroll
      for (int j = 0; j < 4; ++j) {
        const int l = l0 + cn0 + j * 16 + col;
        const float y = acc[i][j][r] + bi;
        if constexpr (MODE == 0) {
          const int xx = (co << 2) + (l >> 9);
          const int hh = (l >> 6) & 7;
          const int dd = l & 63;
          ((ushort*)outp)[((size_t)(b * NH + hh) * LL + xx) * HD + dd] = f2bf(y);
        } else if constexpr (MODE == 1) {
          const int xx = (co << 2) + (l >> 9);
          const int hh = (l >> 6) & 7;
          const int dd = l & 63;
          ((ushort*)outp)[((size_t)(b * NH + hh) * HD + dd) * LL + xx] = f2bf(y);
        } else {
          ((float*)outp)[(size_t)(b * CC + co) * LL + l] = y;
        }
      }
    }
  }
}

// ---------------------------------------------------------------------------
// Attention: per block one (b,h) x 128-row Q tile; loop over 32 y-tiles of 64.
// No max-subtraction (logits bounded): O += exp(S/64) V; denom in registers via
// quad-butterfly.  P round-trips through wave-private LDS rows -> 0 barriers.
// Output scattered back to [b][c][l] bf16 for the fc conv.
// ---------------------------------------------------------------------------
__global__ __launch_bounds__(256, 2)
void attn_k(const ushort* __restrict__ qh, const ushort* __restrict__ kh,
            const ushort* __restrict__ vt, ushort* __restrict__ o)
{
  const int x0 = blockIdx.x * 128;
  const int bh = blockIdx.y;
  const int b = bh >> 3, h = bh & 7;
  const int tid = threadIdx.x, lane = tid & 63, wv = tid >> 6;
  const int col = lane & 15, quad = lane >> 4;
  const int wx = wv * 32;   // wave-private 32 x-rows

  __shared__ ushort Ps[128 * 88];   // stride 88: 16B-aligned rows, 2-way-max banks

  const ushort* Qg = qh + (size_t)bh * (LL * HD);
  const ushort* Kg = kh + (size_t)bh * (LL * HD);
  const ushort* Vg = vt + (size_t)bh * (HD * LL);

  // Q fragments straight from global (A-operand layout: m=lane&15, k=quad*8+j)
  bf16x8 aq[2][2];
#pragma unroll
  for (int i = 0; i < 2; ++i)
#pragma unroll
    for (int kk = 0; kk < 2; ++kk)
      aq[i][kk] = *(const bf16x8*)(Qg + (size_t)(x0 + wx + i * 16 + col) * HD + kk * 32 + quad * 8);

  f32x4 oacc[2][4] = {};
  float rtot[2][4] = {};

  for (int yt = 0; yt < 32; ++yt) {
    const int y0 = yt * 64;
    // S = Q K^T  (K rows are the B-operand: Bt[n=y][k=d])
    f32x4 sacc[2][4] = {};
#pragma unroll
    for (int kk = 0; kk < 2; ++kk) {
#pragma unroll
      for (int j = 0; j < 4; ++j) {
        bf16x8 bk = *(const bf16x8*)(Kg + (size_t)(y0 + j * 16 + col) * HD + kk * 32 + quad * 8);
        sacc[0][j] = __builtin_amdgcn_mfma_f32_16x16x32_bf16(aq[0][kk], bk, sacc[0][j], 0, 0, 0);
        sacc[1][j] = __builtin_amdgcn_mfma_f32_16x16x32_bf16(aq[1][kk], bk, sacc[1][j], 0, 0, 0);
      }
    }
    // exp, row-sum partials, P -> LDS (wave-private rows)
    float rs[2][4] = {};
#pragma unroll
    for (int i = 0; i < 2; ++i)
#pragma unroll
      for (int j = 0; j < 4; ++j)
#pragma unroll
        for (int r = 0; r < 4; ++r) {
          float p = __expf(sacc[i][j][r] * 0.015625f);
          ushort pb = f2bf(p);
          rs[i][r] += bf2f(pb);   // denom matches bf16-rounded numerator
          Ps[(wx + i * 16 + quad * 4 + r) * 88 + j * 16 + col] = pb;
        }
    // butterfly across the 16 lanes of the quad (one quad owns 4 rows)
#pragma unroll
    for (int i = 0; i < 2; ++i)
#pragma unroll
      for (int r = 0; r < 4; ++r) {
        float v = rs[i][r];
        v += __shfl_xor(v, 1); v += __shfl_xor(v, 2);
        v += __shfl_xor(v, 4); v += __shfl_xor(v, 8);
        rtot[i][r] += v;
      }
    // O += P V   (V^T rows are the B-operand: Bt[n=d][k=y])
#pragma unroll
    for (int kk = 0; kk < 2; ++kk) {
      bf16x8 ap0 = *(const bf16x8*)&Ps[(wx + col) * 88 + kk * 32 + quad * 8];
      bf16x8 ap1 = *(const bf16x8*)&Ps[(wx + 16 + col) * 88 + kk * 32 + quad * 8];
#pragma unroll
      for (int j = 0; j < 4; ++j) {
        bf16x8 bv = *(const bf16x8*)(Vg + (size_t)(j * 16 + col) * LL + y0 + kk * 32 + quad * 8);
        oacc[0][j] = __builtin_amdgcn_mfma_f32_16x16x32_bf16(ap0, bv, oacc[0][j], 0, 0, 0);
        oacc[1][j] = __builtin_amdgcn_mfma_f32_16x16x32_bf16(ap1, bv, oacc[1][j], 0, 0, 0);
      }
    }
  }

  // normalize + scatter to [b][c][l] bf16  (flat = x*512 + h*64 + d)
#pragma unroll
  for (int i = 0; i < 2; ++i) {
#pragma unroll
    for (int r = 0; r < 4; ++r) {
      const int xg = x0 + wx + i * 16 + quad * 4 + r;
      const float inv = 1.f / rtot[i][r];
#pragma unroll
      for (int j = 0; j < 4; ++j) {
        const int d = j * 16 + col;
        const int flat = xg * 512 + h * 64 + d;
        const int c = flat >> 11, l = flat & 2047;
        o[((size_t)(b * CC + c) << 11) + l] = f2bf(oacc[i][j][r] * inv);
      }
    }
  }
}

// ---------------------------------------------------------------------------
extern "C" void kernel_launch(void* const* d_in, const int* in_sizes, int n_in,
                              void* d_out, int out_size, void* d_ws, size_t ws_size,
                              hipStream_t stream) {
  const float* q    = (const float*)d_in[0];
  const float* k    = (const float*)d_in[1];
  const float* v    = (const float*)d_in[2];
  const float* wq_w = (const float*)d_in[3];
  const float* wq_b = (const float*)d_in[4];
  const float* wk_w = (const float*)d_in[5];
  const float* wk_b = (const float*)d_in[6];
  const float* wv_w = (const float*)d_in[7];
  const float* wv_b = (const float*)d_in[8];
  const float* fc_w = (const float*)d_in[9];
  const float* fc_b = (const float*)d_in[10];

  char* ws = (char*)d_ws;
  const size_t WSZ = (size_t)CC * KK * sizeof(ushort);          // 1.5 MB per conv
  const size_t HSZ = (size_t)BB * NH * LL * HD * sizeof(ushort); // 8.4 MB per tensor
  ushort* Wtq = (ushort*)(ws);
  ushort* Wtk = (ushort*)(ws + WSZ);
  ushort* Wtv = (ushort*)(ws + 2 * WSZ);
  ushort* Wtf = (ushort*)(ws + 3 * WSZ);
  ushort* qh  = (ushort*)(ws + 4 * WSZ);
  ushort* kh  = (ushort*)(ws + 4 * WSZ + HSZ);
  ushort* vt  = (ushort*)(ws + 4 * WSZ + 2 * HSZ);
  ushort* ob  = (ushort*)(ws + 4 * WSZ + 3 * HSZ);
  // total ws use: ~39.8 MB

  prep_w<<<(4 * CC * KK + 255) / 256, 256, 0, stream>>>(wq_w, wk_w, wv_w, fc_w, Wtq);

  conv_k<0, float><<<dim3(16, 8, 4), 256, 0, stream>>>(q, Wtq, wq_b, qh);
  conv_k<0, float><<<dim3(16, 8, 4), 256, 0, stream>>>(k, Wtk, wk_b, kh);
  conv_k<1, float><<<dim3(16, 8, 4), 256, 0, stream>>>(v, Wtv, wv_b, vt);

  attn_k<<<dim3(16, 32), 256, 0, stream>>>(qh, kh, vt, ob);

  conv_k<2, ushort><<<dim3(16, 8, 4), 256, 0, stream>>>(ob, Wtf, fc_b, (float*)d_out);
}

// Round 2
// 404.795 us; speedup vs baseline: 2.4747x; 2.4747x over previous
//
#include <hip/hip_runtime.h>
#include <hip/hip_bf16.h>

#define BB 4
#define NH 8
#define HD 64
#define CC 512
#define LL 2048
#define KK 1536   // C*3, K index = t*512 + ci
#define LPAD 2050 // padded rows of xT: row 0 and row 2049 are zeros

typedef float f32x4 __attribute__((ext_vector_type(4)));
typedef short bf16x8 __attribute__((ext_vector_type(8)));

static __device__ __forceinline__ ushort f2bf(float f) {
  union { float f; unsigned u; } v; v.f = f;
  unsigned r = v.u + 0x7fffu + ((v.u >> 16) & 1u);   // RNE
  return (ushort)(r >> 16);
}
static __device__ __forceinline__ float bf2f(ushort u) {
  union { unsigned u; float f; } v; v.u = ((unsigned)u) << 16;
  return v.f;
}
static __device__ __forceinline__ void gload16(const ushort* g, ushort* l) {
  __builtin_amdgcn_global_load_lds((const __attribute__((address_space(1))) void*)g,
                                   (__attribute__((address_space(3))) void*)l, 16, 0, 0);
}

// ---------------------------------------------------------------------------
// Weight prep: W[co][ci][t] fp32 -> W'[co][t*512+ci] bf16, for all 4 convs.
// ---------------------------------------------------------------------------
__global__ void prep_w(const float* __restrict__ w0, const float* __restrict__ w1,
                       const float* __restrict__ w2, const float* __restrict__ w3,
                       ushort* __restrict__ out)
{
  int i = blockIdx.x * 256 + threadIdx.x;
  const int per = CC * KK;
  if (i >= 4 * per) return;
  int cidx = i / per;
  int rem  = i - cidx * per;
  int co   = rem / KK;
  int kk   = rem - co * KK;
  int t = kk >> 9, ci = kk & 511;
  const float* w = (cidx == 0) ? w0 : (cidx == 1) ? w1 : (cidx == 2) ? w2 : w3;
  out[i] = f2bf(w[((size_t)co * CC + ci) * 3 + t]);
}

// ---------------------------------------------------------------------------
// Transpose+cast: in[b][c][l] (fp32 or bf16) -> xT[b][l+1][c] bf16, with
// zero rows at l=-1 and l=2048.  64x64 tiles via LDS.
// ---------------------------------------------------------------------------
template<typename TIn>
__global__ __launch_bounds__(256, 2)
void transpose_k(const TIn* __restrict__ in, ushort* __restrict__ outT)
{
  const int b  = blockIdx.z;
  const int c0 = blockIdx.y * 64;
  const int l0 = blockIdx.x * 64;
  const int tid = threadIdx.x;
  __shared__ ushort T[64 * 72];
  const TIn* xb = in + (size_t)b * CC * LL;
  ushort* ob = outT + (size_t)b * (LPAD * CC);
  {
    const int rr = tid >> 4;      // 0..15
    const int f4 = tid & 15;      // 0..15
#pragma unroll
    for (int it = 0; it < 4; ++it) {
      const int cc = rr + it * 16;
      ushort s[4];
      if constexpr (sizeof(TIn) == 4) {
        float4 vv = *(const float4*)((const float*)xb + (size_t)(c0 + cc) * LL + l0 + f4 * 4);
        s[0] = f2bf(vv.x); s[1] = f2bf(vv.y); s[2] = f2bf(vv.z); s[3] = f2bf(vv.w);
      } else {
        *(ushort4*)s = *(const ushort4*)((const ushort*)xb + (size_t)(c0 + cc) * LL + l0 + f4 * 4);
      }
      *(ushort4*)&T[cc * 72 + f4 * 4] = *(ushort4*)s;
    }
  }
  __syncthreads();
  {
    const int lr = tid >> 3;     // 0..31
    const int ch = tid & 7;      // 0..7
#pragma unroll
    for (int it = 0; it < 2; ++it) {
      const int ll = lr + it * 32;
      ushort tmp[8];
#pragma unroll
      for (int e = 0; e < 8; ++e) tmp[e] = T[(ch * 8 + e) * 72 + ll];
      *(uint4*)(ob + (size_t)(l0 + ll + 1) * CC + c0 + ch * 8) = *(uint4*)tmp;
    }
  }
  // zero the halo rows
  if (blockIdx.x == 0 && tid < 8) {
    uint4 z4 = make_uint4(0, 0, 0, 0);
    *(uint4*)(ob + c0 + tid * 8) = z4;
  }
  if (blockIdx.x == (LL / 64 - 1) && tid >= 248) {
    uint4 z4 = make_uint4(0, 0, 0, 0);
    *(uint4*)(ob + (size_t)(LPAD - 1) * CC + c0 + (tid - 248) * 8) = z4;
  }
}

// ---------------------------------------------------------------------------
// conv1d(k=3,same) as implicit GEMM on pre-transposed bf16 input.
// Tile M=64(co) x N=128(l), BK=32.  Staging = 3x global_load_lds(16B)/thread.
// Key trick: a t-step of the kernel tap equals one padded row of xT, so the
// global staging address is linear in k0 (base + k0).
// mode 0: out heads [b][h][x][d] bf16 (q,k)
// mode 1: out heads-T [b][h][d][x] bf16 (v)
// mode 2: out [b][co][l] fp32 (final fc)
// ---------------------------------------------------------------------------
__global__ __launch_bounds__(256, 2)
void conv_k(const ushort* __restrict__ xT, const ushort* __restrict__ Wt,
            const float* __restrict__ bias, void* __restrict__ outp, int mode)
{
  const int b   = blockIdx.z;
  const int co0 = blockIdx.y * 64;
  const int l0  = blockIdx.x * 128;
  const int tid = threadIdx.x;
  const int lane = tid & 63;
  const int w    = tid >> 6;
  const int col  = lane & 15, quad = lane >> 4;

  __shared__ ushort Asl[64 * 32];    // unpadded: global_load_lds needs lane*16 layout
  __shared__ ushort Bsl[128 * 32];

  const ushort* xb = xT + (size_t)b * (LPAD * CC);

  const int arow = tid >> 2, acol = (tid & 3) * 8;
  const ushort* ag  = Wt + (size_t)(co0 + arow) * KK + acol;
  const ushort* bg0 = xb + (size_t)(l0 + arow) * CC + acol;        // B rows 0..63
  const ushort* bg1 = xb + (size_t)(l0 + 64 + arow) * CC + acol;   // B rows 64..127
  ushort* al  = &Asl[tid * 8];          // byte offset tid*16
  ushort* bl0 = &Bsl[tid * 8];
  ushort* bl1 = &Bsl[2048 + tid * 8];

  f32x4 acc[2][4] = {};
  const int cm0 = (w & 1) * 32;
  const int cn0 = (w >> 1) * 64;

  for (int k0 = 0; k0 < KK; k0 += 32) {
    gload16(ag + k0, al);
    gload16(bg0 + k0, bl0);
    gload16(bg1 + k0, bl1);
    __syncthreads();
    bf16x8 af[2], bfr[4];
#pragma unroll
    for (int i = 0; i < 2; ++i)
      af[i] = *(const bf16x8*)&Asl[(cm0 + i * 16 + col) * 32 + quad * 8];
#pragma unroll
    for (int j = 0; j < 4; ++j)
      bfr[j] = *(const bf16x8*)&Bsl[(cn0 + j * 16 + col) * 32 + quad * 8];
#pragma unroll
    for (int i = 0; i < 2; ++i)
#pragma unroll
      for (int j = 0; j < 4; ++j)
        acc[i][j] = __builtin_amdgcn_mfma_f32_16x16x32_bf16(af[i], bfr[j], acc[i][j], 0, 0, 0);
    __syncthreads();
  }

  // epilogue: C/D layout row = quad*4+r (co), col = lane&15 (l)
#pragma unroll
  for (int i = 0; i < 2; ++i) {
#pragma unroll
    for (int r = 0; r < 4; ++r) {
      const int co = co0 + cm0 + i * 16 + quad * 4 + r;
      const float bi = bias[co];
#pragma unroll
      for (int j = 0; j < 4; ++j) {
        const int l = l0 + cn0 + j * 16 + col;
        const float y = acc[i][j][r] + bi;
        if (mode == 0) {
          const int xx = (co << 2) + (l >> 9);
          const int hh = (l >> 6) & 7;
          const int dd = l & 63;
          ((ushort*)outp)[((size_t)(b * NH + hh) * LL + xx) * HD + dd] = f2bf(y);
        } else if (mode == 1) {
          const int xx = (co << 2) + (l >> 9);
          const int hh = (l >> 6) & 7;
          const int dd = l & 63;
          ((ushort*)outp)[((size_t)(b * NH + hh) * HD + dd) * LL + xx] = f2bf(y);
        } else {
          ((float*)outp)[(size_t)(b * CC + co) * LL + l] = y;
        }
      }
    }
  }
}

// ---------------------------------------------------------------------------
// Attention: per block one (b,h) x 128-row Q tile; loop over 32 y-tiles of 64.
// No max-subtraction (logits bounded): O += exp(S/64) V; denom in registers via
// quad-butterfly.  P round-trips through wave-private LDS rows -> 0 barriers.
// Output scattered back to [b][c][l] bf16 for the fc conv.
// ---------------------------------------------------------------------------
__global__ __launch_bounds__(256, 2)
void attn_k(const ushort* __restrict__ qh, const ushort* __restrict__ kh,
            const ushort* __restrict__ vt, ushort* __restrict__ o)
{
  const int x0 = blockIdx.x * 128;
  const int bh = blockIdx.y;
  const int b = bh >> 3, h = bh & 7;
  const int tid = threadIdx.x, lane = tid & 63, wv = tid >> 6;
  const int col = lane & 15, quad = lane >> 4;
  const int wx = wv * 32;   // wave-private 32 x-rows

  __shared__ ushort Ps[128 * 88];   // stride 88: 16B-aligned rows, 2-way-max banks

  const ushort* Qg = qh + (size_t)bh * (LL * HD);
  const ushort* Kg = kh + (size_t)bh * (LL * HD);
  const ushort* Vg = vt + (size_t)bh * (HD * LL);

  // Q fragments straight from global (A-operand layout: m=lane&15, k=quad*8+j)
  bf16x8 aq[2][2];
#pragma unroll
  for (int i = 0; i < 2; ++i)
#pragma unroll
    for (int kk = 0; kk < 2; ++kk)
      aq[i][kk] = *(const bf16x8*)(Qg + (size_t)(x0 + wx + i * 16 + col) * HD + kk * 32 + quad * 8);

  f32x4 oacc[2][4] = {};
  float rtot[2][4] = {};

  for (int yt = 0; yt < 32; ++yt) {
    const int y0 = yt * 64;
    // S = Q K^T  (K rows are the B-operand: Bt[n=y][k=d])
    f32x4 sacc[2][4] = {};
#pragma unroll
    for (int kk = 0; kk < 2; ++kk) {
#pragma unroll
      for (int j = 0; j < 4; ++j) {
        bf16x8 bk = *(const bf16x8*)(Kg + (size_t)(y0 + j * 16 + col) * HD + kk * 32 + quad * 8);
        sacc[0][j] = __builtin_amdgcn_mfma_f32_16x16x32_bf16(aq[0][kk], bk, sacc[0][j], 0, 0, 0);
        sacc[1][j] = __builtin_amdgcn_mfma_f32_16x16x32_bf16(aq[1][kk], bk, sacc[1][j], 0, 0, 0);
      }
    }
    // exp, row-sum partials, P -> LDS (wave-private rows)
    float rs[2][4] = {};
#pragma unroll
    for (int i = 0; i < 2; ++i)
#pragma unroll
      for (int j = 0; j < 4; ++j)
#pragma unroll
        for (int r = 0; r < 4; ++r) {
          float p = __expf(sacc[i][j][r] * 0.015625f);
          ushort pb = f2bf(p);
          rs[i][r] += bf2f(pb);   // denom matches bf16-rounded numerator
          Ps[(wx + i * 16 + quad * 4 + r) * 88 + j * 16 + col] = pb;
        }
    // butterfly across the 16 lanes of the quad (one quad owns 4 rows)
#pragma unroll
    for (int i = 0; i < 2; ++i)
#pragma unroll
      for (int r = 0; r < 4; ++r) {
        float v = rs[i][r];
        v += __shfl_xor(v, 1); v += __shfl_xor(v, 2);
        v += __shfl_xor(v, 4); v += __shfl_xor(v, 8);
        rtot[i][r] += v;
      }
    // O += P V   (V^T rows are the B-operand: Bt[n=d][k=y])
#pragma unroll
    for (int kk = 0; kk < 2; ++kk) {
      bf16x8 ap0 = *(const bf16x8*)&Ps[(wx + col) * 88 + kk * 32 + quad * 8];
      bf16x8 ap1 = *(const bf16x8*)&Ps[(wx + 16 + col) * 88 + kk * 32 + quad * 8];
#pragma unroll
      for (int j = 0; j < 4; ++j) {
        bf16x8 bv = *(const bf16x8*)(Vg + (size_t)(j * 16 + col) * LL + y0 + kk * 32 + quad * 8);
        oacc[0][j] = __builtin_amdgcn_mfma_f32_16x16x32_bf16(ap0, bv, oacc[0][j], 0, 0, 0);
        oacc[1][j] = __builtin_amdgcn_mfma_f32_16x16x32_bf16(ap1, bv, oacc[1][j], 0, 0, 0);
      }
    }
  }

  // normalize + scatter to [b][c][l] bf16  (flat = x*512 + h*64 + d)
#pragma unroll
  for (int i = 0; i < 2; ++i) {
#pragma unroll
    for (int r = 0; r < 4; ++r) {
      const int xg = x0 + wx + i * 16 + quad * 4 + r;
      const float inv = 1.f / rtot[i][r];
#pragma unroll
      for (int j = 0; j < 4; ++j) {
        const int d = j * 16 + col;
        const int flat = xg * 512 + h * 64 + d;
        const int c = flat >> 11, l = flat & 2047;
        o[((size_t)(b * CC + c) << 11) + l] = f2bf(oacc[i][j][r] * inv);
      }
    }
  }
}

// ---------------------------------------------------------------------------
extern "C" void kernel_launch(void* const* d_in, const int* in_sizes, int n_in,
                              void* d_out, int out_size, void* d_ws, size_t ws_size,
                              hipStream_t stream) {
  const float* q    = (const float*)d_in[0];
  const float* k    = (const float*)d_in[1];
  const float* v    = (const float*)d_in[2];
  const float* wq_w = (const float*)d_in[3];
  const float* wq_b = (const float*)d_in[4];
  const float* wk_w = (const float*)d_in[5];
  const float* wk_b = (const float*)d_in[6];
  const float* wv_w = (const float*)d_in[7];
  const float* wv_b = (const float*)d_in[8];
  const float* fc_w = (const float*)d_in[9];
  const float* fc_b = (const float*)d_in[10];

  char* ws = (char*)d_ws;
  const size_t WSZ = (size_t)CC * KK * sizeof(ushort);            // 1.5 MB per conv
  const size_t HSZ = (size_t)BB * NH * LL * HD * sizeof(ushort);  // 8.39 MB per head tensor
  const size_t XSZ = (size_t)BB * LPAD * CC * sizeof(ushort);     // 8.40 MB padded xT

  ushort* Wt  = (ushort*)(ws);                         // 4 weight sets, 6 MB
  ushort* qh  = (ushort*)(ws + 4 * WSZ);
  ushort* kh  = (ushort*)(ws + 4 * WSZ + HSZ);
  ushort* vt  = (ushort*)(ws + 4 * WSZ + 2 * HSZ);
  ushort* xTb = (ushort*)(ws + 4 * WSZ + 3 * HSZ);     // shared transpose buffer
  // aliases (lifetimes disjoint):
  ushort* ob  = xTb;            // attn output [b][c][l]; xT dead after v-conv
  ushort* obT = qh;             // padded transpose of ob; qh(+kh) dead after attn
  // total ws use: 4*WSZ + 3*HSZ + XSZ  ~= 39.85 MB

  prep_w<<<(4 * CC * KK + 255) / 256, 256, 0, stream>>>(wq_w, wk_w, wv_w, fc_w, Wt);

  // q
  transpose_k<float><<<dim3(32, 8, 4), 256, 0, stream>>>(q, xTb);
  conv_k<<<dim3(16, 8, 4), 256, 0, stream>>>(xTb, Wt + 0 * CC * KK, wq_b, qh, 0);
  // k
  transpose_k<float><<<dim3(32, 8, 4), 256, 0, stream>>>(k, xTb);
  conv_k<<<dim3(16, 8, 4), 256, 0, stream>>>(xTb, Wt + 1 * CC * KK, wk_b, kh, 0);
  // v
  transpose_k<float><<<dim3(32, 8, 4), 256, 0, stream>>>(v, xTb);
  conv_k<<<dim3(16, 8, 4), 256, 0, stream>>>(xTb, Wt + 2 * CC * KK, wv_b, vt, 1);

  attn_k<<<dim3(16, 32), 256, 0, stream>>>(qh, kh, vt, ob);

  transpose_k<ushort><<<dim3(32, 8, 4), 256, 0, stream>>>(ob, obT);
  conv_k<<<dim3(16, 8, 4), 256, 0, stream>>>(obT, Wt + 3 * CC * KK, fc_b, (float*)d_out, 2);
}